// Round 1
// baseline (238.322 us; speedup 1.0000x reference)
//
#include <hip/hip_runtime.h>

// MV_GCN on MI355X — round 0: correct fp32 baseline, 3 kernels.
// Formulation: per (graph,view) the GCN aggregation over 6670 random edges is a
// dense 116x116 adjacency matmul. A_hat[d][s] = sum_e w_e * dinv[s]*dinv[d],
// diagonal += dinv^2 (self loop), deg = rowsum of raw A (so edges read ONCE).
// out = A_hat @ (X @ W) + b, then max over 128 channels -> feat[B,232] -> MLP.
//
// ws layout: H tiles [512][116][128] f32 (30.4 MB) then feat [256][232] f32.

#define NB 256
#define NODES 116
#define FEAT 115
#define LENN 6670
#define SEG2 13456
#define HID 128
#define HC 512
#define LSTR 120   // padded LDS row stride (120*4 B = 480, 16B-aligned rows)

// ---------------- K1: H = X @ W_v per (g,v) tile ----------------
// 256 thr: cg = t&63 -> 2 cols, rg = t>>6 -> 29 rows (116 = 4*29 exact).
// x tile in LDS (b128 full-wave broadcasts), W streamed from L2 (float2,
// reused across 29 rows -> ~0.14 B/FMA of W traffic).
__global__ __launch_bounds__(256) void k_h_gemm(
    const float* __restrict__ x, const float* __restrict__ W1,
    const float* __restrict__ W2, float* __restrict__ Hws)
{
  __shared__ float sX[NODES * LSTR];
  const int bid = blockIdx.x;
  const int g = bid >> 1, v = bid & 1;
  const int tid = threadIdx.x;
  const float* __restrict__ W = v ? W2 : W1;
  const float* __restrict__ xg = x + (size_t)(g * 232 + v * 116) * FEAT;

  for (int i = tid; i < NODES * FEAT; i += 256) {
    int r = i / FEAT;           // const divisor -> magic mul
    int k = i - r * FEAT;
    sX[r * LSTR + k] = xg[i];   // contiguous global read, coalesced
  }
  __syncthreads();

  const int cg = tid & 63, rg = tid >> 6;
  const int c0 = cg * 2, r0 = rg * 29;

  float2 acc[29];
#pragma unroll
  for (int i = 0; i < 29; ++i) acc[i] = make_float2(0.f, 0.f);

  for (int kc = 0; kc < 28; ++kc) {   // k = 0..111 in chunks of 4
    const int k0 = kc * 4;
    float2 w0 = *(const float2*)(W + (size_t)(k0 + 0) * HID + c0);
    float2 w1 = *(const float2*)(W + (size_t)(k0 + 1) * HID + c0);
    float2 w2 = *(const float2*)(W + (size_t)(k0 + 2) * HID + c0);
    float2 w3 = *(const float2*)(W + (size_t)(k0 + 3) * HID + c0);
#pragma unroll
    for (int i = 0; i < 29; ++i) {
      float4 a = *(const float4*)&sX[(r0 + i) * LSTR + k0];  // 16B-aligned bcast
      acc[i].x += a.x * w0.x + a.y * w1.x + a.z * w2.x + a.w * w3.x;
      acc[i].y += a.x * w0.y + a.y * w1.y + a.z * w2.y + a.w * w3.y;
    }
  }
  for (int k = 112; k < 115; ++k) {   // K tail (115 = 28*4 + 3)
    float2 w = *(const float2*)(W + (size_t)k * HID + c0);
#pragma unroll
    for (int i = 0; i < 29; ++i) {
      float a = sX[(r0 + i) * LSTR + k];
      acc[i].x += a * w.x;
      acc[i].y += a * w.y;
    }
  }

  float* __restrict__ Ht = Hws + (size_t)bid * NODES * HID;
#pragma unroll
  for (int i = 0; i < 29; ++i)
    *(float2*)(Ht + (size_t)(r0 + i) * HID + c0) = acc[i];
}

// ---------------- K2: build A_hat, out = A_hat @ H, channel-max ----------------
__global__ __launch_bounds__(256) void k_agg(
    const int* __restrict__ ei, const float* __restrict__ ew,
    const float* __restrict__ b1, const float* __restrict__ b2,
    const float* __restrict__ Hws, float* __restrict__ featws)
{
  __shared__ float sA[NODES * LSTR];
  __shared__ float dinv[NODES];
  const int bid = blockIdx.x;
  const int g = bid >> 1, v = bid & 1;
  const int tid = threadIdx.x;

  for (int i = tid; i < NODES * LSTR; i += 256) sA[i] = 0.f;
  __syncthreads();

  // one edge pass: A_raw[d][s] += w  (deg recovered as row sums)
  const int eoff = g * SEG2 + v * LENN;
  const int nbase = g * 232 + v * 116;
  const int* __restrict__ srcp = ei + eoff;
  const int* __restrict__ dstp = ei + (size_t)NB * SEG2 + eoff;
  const float* __restrict__ wp = ew + eoff;
  for (int e = tid; e < LENN; e += 256) {
    int s = srcp[e] - nbase;
    int d = dstp[e] - nbase;
    atomicAdd(&sA[d * LSTR + s], wp[e]);
  }
  __syncthreads();

  if (tid < NODES) {
    float sum = 0.f;
    for (int s = 0; s < NODES; ++s) sum += sA[tid * LSTR + s];
    dinv[tid] = rsqrtf(sum + 1.0f);   // deg + 1 (self loop)
  }
  __syncthreads();

  // normalize in place; fold self-loop dinv^2 into the diagonal
  for (int idx = tid; idx < NODES * NODES; idx += 256) {
    int d = idx / NODES;
    int s = idx - d * NODES;
    float di = dinv[d];
    float val = sA[d * LSTR + s] * di * dinv[s];
    if (d == s) val += di * di;
    sA[d * LSTR + s] = val;
  }
  __syncthreads();

  // dense A_hat(116x116, LDS) @ H(116x128, L2) ; same 29x2 register tiling
  const float* __restrict__ bv = v ? b2 : b1;
  const int cg = tid & 63, rg = tid >> 6;
  const int c0 = cg * 2, r0 = rg * 29;
  const float* __restrict__ Ht = Hws + (size_t)bid * NODES * HID;

  float2 bb = *(const float2*)(bv + c0);
  float2 acc[29];
#pragma unroll
  for (int i = 0; i < 29; ++i) acc[i] = bb;

  for (int sc = 0; sc < 29; ++sc) {   // s = 0..115 in chunks of 4 (116 = 29*4)
    const int s0 = sc * 4;
    float2 h0 = *(const float2*)(Ht + (size_t)(s0 + 0) * HID + c0);
    float2 h1 = *(const float2*)(Ht + (size_t)(s0 + 1) * HID + c0);
    float2 h2 = *(const float2*)(Ht + (size_t)(s0 + 2) * HID + c0);
    float2 h3 = *(const float2*)(Ht + (size_t)(s0 + 3) * HID + c0);
#pragma unroll
    for (int i = 0; i < 29; ++i) {
      float4 a = *(const float4*)&sA[(r0 + i) * LSTR + s0];  // full-wave bcast
      acc[i].x += a.x * h0.x + a.y * h1.x + a.z * h2.x + a.w * h3.x;
      acc[i].y += a.x * h0.y + a.y * h1.y + a.z * h2.y + a.w * h3.y;
    }
  }

  // channel max across the 64 lanes of this wave (each lane holds 2 channels)
#pragma unroll
  for (int i = 0; i < 29; ++i) {
    float m = fmaxf(acc[i].x, acc[i].y);
#pragma unroll
    for (int off = 32; off >= 1; off >>= 1)
      m = fmaxf(m, __shfl_xor(m, off, 64));
    if (cg == 0)
      featws[g * 232 + 2 * (r0 + i) + v] = m;   // stack([x1,x2],1).reshape
  }
}

// ---------------- K3: MLP  relu(feat@W6+b6)@W7+b7 ----------------
__global__ __launch_bounds__(256) void k_mlp(
    const float* __restrict__ featws, const float* __restrict__ W6,
    const float* __restrict__ b6, const float* __restrict__ W7,
    const float* __restrict__ b7, float* __restrict__ out)
{
  __shared__ float sf[232];
  __shared__ float red[4];
  const int g = blockIdx.x, tid = threadIdx.x;
  if (tid < 232) sf[tid] = featws[g * 232 + tid];
  __syncthreads();

  const int c0 = tid * 2;
  float a0 = b6[c0], a1 = b6[c0 + 1];
  for (int k = 0; k < 232; ++k) {
    float f = sf[k];
    float2 w = *(const float2*)(W6 + (size_t)k * HC + c0);
    a0 += f * w.x;
    a1 += f * w.y;
  }
  a0 = fmaxf(a0, 0.f);
  a1 = fmaxf(a1, 0.f);
  float2 w7 = *(const float2*)(W7 + c0);
  float p = a0 * w7.x + a1 * w7.y;
#pragma unroll
  for (int off = 32; off >= 1; off >>= 1) p += __shfl_xor(p, off, 64);
  if ((tid & 63) == 0) red[tid >> 6] = p;
  __syncthreads();
  if (tid == 0) out[g] = red[0] + red[1] + red[2] + red[3] + b7[0];
}

extern "C" void kernel_launch(void* const* d_in, const int* in_sizes, int n_in,
                              void* d_out, int out_size, void* d_ws, size_t ws_size,
                              hipStream_t stream)
{
  const float* x  = (const float*)d_in[0];
  const int*   ei = (const int*)d_in[1];
  const float* ew = (const float*)d_in[2];
  // d_in[3] = batch (unused by reference)
  const float* W1 = (const float*)d_in[4];
  const float* b1 = (const float*)d_in[5];
  const float* W2 = (const float*)d_in[6];
  const float* b2 = (const float*)d_in[7];
  const float* W6 = (const float*)d_in[8];
  const float* b6 = (const float*)d_in[9];
  const float* W7 = (const float*)d_in[10];
  const float* b7 = (const float*)d_in[11];

  float* Hws    = (float*)d_ws;                       // 512*116*128 f32 = 30.4 MB
  float* featws = Hws + (size_t)512 * NODES * HID;    // 256*232 f32
  float* out    = (float*)d_out;

  hipLaunchKernelGGL(k_h_gemm, dim3(2 * NB), dim3(256), 0, stream, x, W1, W2, Hws);
  hipLaunchKernelGGL(k_agg,    dim3(2 * NB), dim3(256), 0, stream, ei, ew, b1, b2, Hws, featws);
  hipLaunchKernelGGL(k_mlp,    dim3(NB),     dim3(256), 0, stream, featws, W6, b6, W7, b7, out);
}

// Round 2
// 209.211 us; speedup vs baseline: 1.1391x; 1.1391x over previous
//
#include <hip/hip_runtime.h>

// MV_GCN on MI355X — round 2: latency attack.
// 512-thread blocks (4 waves/SIMD at 2 blocks/CU) + register double-buffered
// prefetch of the L2-streamed GEMM operand (W in K1, H in K2).
// Same math as round 1: dense 116x116 A_hat per (g,v), built once from edges.

#define NB 256
#define NODES 116
#define FEAT 115
#define LENN 6670
#define SEG2 13456
#define HID 128
#define HC 512
#define LSTR 120   // padded LDS row stride (480 B, 16B-aligned rows)

// ---------------- K1: H = X @ W_v per (g,v) tile ----------------
// 512 thr: cg = t&63 -> 2 cols, rg = t>>6 -> rows rg, rg+8, ... (15 slots,
// clamped to 115; duplicate rows write identical values -> benign).
__global__ __launch_bounds__(512, 4) void k_h_gemm(
    const float* __restrict__ x, const float* __restrict__ W1,
    const float* __restrict__ W2, float* __restrict__ Hws)
{
  __shared__ __align__(16) float sX[NODES * LSTR];
  const int bid = blockIdx.x;
  const int g = bid >> 1, v = bid & 1;
  const int tid = threadIdx.x;
  const float* __restrict__ W = v ? W2 : W1;
  const float* __restrict__ xg = x + (size_t)(g * 232 + v * 116) * FEAT;

  // stage X with zeroed pad columns (k=115..119) so the K-loop is uniform
  for (int i = tid; i < NODES * LSTR; i += 512) {
    int r = i / LSTR;
    int k = i - r * LSTR;
    sX[i] = (k < FEAT) ? xg[r * FEAT + k] : 0.f;
  }
  __syncthreads();

  const int cg = tid & 63, rg = tid >> 6;
  const int c0 = cg * 2;
  const float* __restrict__ Wc = W + c0;

  float2 acc[15];
#pragma unroll
  for (int i = 0; i < 15; ++i) acc[i] = make_float2(0.f, 0.f);

  float2 wc[4], wn[4];
#pragma unroll
  for (int j = 0; j < 4; ++j) wn[j] = *(const float2*)(Wc + (size_t)j * HID);

  for (int kc = 0; kc < 29; ++kc) {          // k = 0..115 (115 = X pad zero)
#pragma unroll
    for (int j = 0; j < 4; ++j) wc[j] = wn[j];
    if (kc < 27) {                           // prefetch next 4 W rows
      const int kn = 4 * (kc + 1);
#pragma unroll
      for (int j = 0; j < 4; ++j)
        wn[j] = *(const float2*)(Wc + (size_t)(kn + j) * HID);
    } else if (kc == 27) {                   // tail rows 112..114 + zero row
#pragma unroll
      for (int j = 0; j < 3; ++j)
        wn[j] = *(const float2*)(Wc + (size_t)(112 + j) * HID);
      wn[3] = make_float2(0.f, 0.f);
    }
    const int k0 = 4 * kc;
#pragma unroll
    for (int i = 0; i < 15; ++i) {
      int r = rg + 8 * i;
      r = (r < NODES) ? r : (NODES - 1);
      float4 a = *(const float4*)&sX[r * LSTR + k0];  // wave-uniform bcast
      acc[i].x = fmaf(a.x, wc[0].x, acc[i].x);
      acc[i].x = fmaf(a.y, wc[1].x, acc[i].x);
      acc[i].x = fmaf(a.z, wc[2].x, acc[i].x);
      acc[i].x = fmaf(a.w, wc[3].x, acc[i].x);
      acc[i].y = fmaf(a.x, wc[0].y, acc[i].y);
      acc[i].y = fmaf(a.y, wc[1].y, acc[i].y);
      acc[i].y = fmaf(a.z, wc[2].y, acc[i].y);
      acc[i].y = fmaf(a.w, wc[3].y, acc[i].y);
    }
  }

  float* __restrict__ Ht = Hws + (size_t)bid * NODES * HID;
#pragma unroll
  for (int i = 0; i < 15; ++i) {
    int r = rg + 8 * i;
    r = (r < NODES) ? r : (NODES - 1);   // duplicate rows store same value
    *(float2*)(Ht + (size_t)r * HID + c0) = acc[i];
  }
}

// ---------------- K2: build A_hat, out = A_hat @ H, channel-max ----------------
__global__ __launch_bounds__(512, 4) void k_agg(
    const int* __restrict__ ei, const float* __restrict__ ew,
    const float* __restrict__ b1, const float* __restrict__ b2,
    const float* __restrict__ Hws, float* __restrict__ featws)
{
  __shared__ __align__(16) float sA[NODES * LSTR];
  __shared__ float dinv[NODES];
  const int bid = blockIdx.x;
  const int g = bid >> 1, v = bid & 1;
  const int tid = threadIdx.x;

  const float4 z4 = make_float4(0.f, 0.f, 0.f, 0.f);
  for (int i = tid; i < (NODES * LSTR) / 4; i += 512) ((float4*)sA)[i] = z4;
  __syncthreads();

  // one edge pass: A_raw[d][s] += w (deg recovered as row sums)
  const int eoff = g * SEG2 + v * LENN;
  const int nbase = g * 232 + v * 116;
  const int* __restrict__ srcp = ei + eoff;
  const int* __restrict__ dstp = ei + (size_t)NB * SEG2 + eoff;
  const float* __restrict__ wp = ew + eoff;
#pragma unroll 2
  for (int e = tid; e < LENN; e += 512) {
    int s = srcp[e] - nbase;
    int d = dstp[e] - nbase;
    atomicAdd(&sA[d * LSTR + s], wp[e]);
  }
  __syncthreads();

  // deg: 4 threads per row (stride-29 starts break the stride-120 bank aliasing)
  if (tid < 4 * NODES) {
    const int r = tid >> 2, q = tid & 3;
    const float* row = &sA[r * LSTR + q * 29];
    float s = 0.f;
#pragma unroll
    for (int j = 0; j < 29; ++j) s += row[j];
    s += __shfl_xor(s, 1, 64);
    s += __shfl_xor(s, 2, 64);
    if (q == 0) dinv[r] = rsqrtf(s + 1.0f);   // deg + 1 self-loop
  }
  __syncthreads();

  // normalize in place; fold self-loop dinv^2 into the diagonal
  for (int idx = tid; idx < NODES * NODES; idx += 512) {
    int d = idx / NODES;
    int s = idx - d * NODES;
    float di = dinv[d];
    float val = sA[d * LSTR + s] * (di * dinv[s]);
    if (d == s) val += di * di;
    sA[d * LSTR + s] = val;
  }
  __syncthreads();

  // dense A_hat(LDS) @ H(L2, double-buffered) ; 15x2 register tile
  const float* __restrict__ bv = v ? b2 : b1;
  const int cg = tid & 63, rg = tid >> 6;
  const int c0 = cg * 2;
  const float* __restrict__ Ht = Hws + (size_t)bid * NODES * HID + c0;

  float2 bb = *(const float2*)(bv + c0);
  float2 acc[15];
#pragma unroll
  for (int i = 0; i < 15; ++i) acc[i] = bb;

  float2 hc[4], hn[4];
#pragma unroll
  for (int j = 0; j < 4; ++j) hn[j] = *(const float2*)(Ht + (size_t)j * HID);

  for (int sc = 0; sc < 29; ++sc) {          // s = 0..115 (116 = 29*4 exact)
#pragma unroll
    for (int j = 0; j < 4; ++j) hc[j] = hn[j];
    if (sc < 28) {
      const int sn = 4 * (sc + 1);
#pragma unroll
      for (int j = 0; j < 4; ++j)
        hn[j] = *(const float2*)(Ht + (size_t)(sn + j) * HID);
    }
    const int s0 = 4 * sc;
#pragma unroll
    for (int i = 0; i < 15; ++i) {
      int r = rg + 8 * i;
      r = (r < NODES) ? r : (NODES - 1);
      float4 a = *(const float4*)&sA[r * LSTR + s0];  // wave-uniform bcast
      acc[i].x = fmaf(a.x, hc[0].x, acc[i].x);
      acc[i].x = fmaf(a.y, hc[1].x, acc[i].x);
      acc[i].x = fmaf(a.z, hc[2].x, acc[i].x);
      acc[i].x = fmaf(a.w, hc[3].x, acc[i].x);
      acc[i].y = fmaf(a.x, hc[0].y, acc[i].y);
      acc[i].y = fmaf(a.y, hc[1].y, acc[i].y);
      acc[i].y = fmaf(a.z, hc[2].y, acc[i].y);
      acc[i].y = fmaf(a.w, hc[3].y, acc[i].y);
    }
  }

  // channel max across the wave (each lane holds 2 of the 128 channels)
#pragma unroll
  for (int i = 0; i < 15; ++i) {
    int r = rg + 8 * i;
    r = (r < NODES) ? r : (NODES - 1);
    float m = fmaxf(acc[i].x, acc[i].y);
#pragma unroll
    for (int off = 32; off >= 1; off >>= 1)
      m = fmaxf(m, __shfl_xor(m, off, 64));
    if (cg == 0)
      featws[g * 232 + 2 * r + v] = m;   // stack([x1,x2],1).reshape (dups same val)
  }
}

// ---------------- K3: MLP  relu(feat@W6+b6)@W7+b7 ----------------
__global__ __launch_bounds__(512) void k_mlp(
    const float* __restrict__ featws, const float* __restrict__ W6,
    const float* __restrict__ b6, const float* __restrict__ W7,
    const float* __restrict__ b7, float* __restrict__ out)
{
  __shared__ float sf[232];
  __shared__ float red[8];
  const int g = blockIdx.x, tid = threadIdx.x;
  if (tid < 232) sf[tid] = featws[g * 232 + tid];
  __syncthreads();

  float a = b6[tid];
  const float* __restrict__ w6p = W6 + tid;
#pragma unroll 8
  for (int k = 0; k < 232; ++k)
    a = fmaf(sf[k], w6p[(size_t)k * HC], a);
  a = fmaxf(a, 0.f);
  float p = a * W7[tid];
#pragma unroll
  for (int off = 32; off >= 1; off >>= 1) p += __shfl_xor(p, off, 64);
  if ((tid & 63) == 0) red[tid >> 6] = p;
  __syncthreads();
  if (tid == 0) {
    float t = b7[0];
#pragma unroll
    for (int i = 0; i < 8; ++i) t += red[i];
    out[g] = t;
  }
}

extern "C" void kernel_launch(void* const* d_in, const int* in_sizes, int n_in,
                              void* d_out, int out_size, void* d_ws, size_t ws_size,
                              hipStream_t stream)
{
  const float* x  = (const float*)d_in[0];
  const int*   ei = (const int*)d_in[1];
  const float* ew = (const float*)d_in[2];
  // d_in[3] = batch (unused by reference)
  const float* W1 = (const float*)d_in[4];
  const float* b1 = (const float*)d_in[5];
  const float* W2 = (const float*)d_in[6];
  const float* b2 = (const float*)d_in[7];
  const float* W6 = (const float*)d_in[8];
  const float* b6 = (const float*)d_in[9];
  const float* W7 = (const float*)d_in[10];
  const float* b7 = (const float*)d_in[11];

  float* Hws    = (float*)d_ws;                       // 512*116*128 f32 = 30.4 MB
  float* featws = Hws + (size_t)512 * NODES * HID;    // 256*232 f32
  float* out    = (float*)d_out;

  hipLaunchKernelGGL(k_h_gemm, dim3(2 * NB), dim3(512), 0, stream, x, W1, W2, Hws);
  hipLaunchKernelGGL(k_agg,    dim3(2 * NB), dim3(512), 0, stream, ei, ew, b1, b2, Hws, featws);
  hipLaunchKernelGGL(k_mlp,    dim3(NB),     dim3(512), 0, stream, featws, W6, b6, W7, b7, out);
}